// Round 7
// baseline (550.804 us; speedup 1.0000x reference)
//
#include <hip/hip_runtime.h>
#include <hip/hip_bf16.h>

#define NN 512
#define CS 384
#define CZ 128
#define NH 12
#define PROJW 1152
#define FEAT 2112
#define OUTC 384

// workspace float offsets (peak 6,635,520 floats = 26.5 MB)
#define WPROJ 0          // [512][1152]
#define WVT   589824     // [480][512]: rows 0-191 v, rows 192-479 vpg
#define WFEAT 835584     // [512][2112]
#define WSC   1916928    // scores fp32 [512][512][12]; later aliased by out partials [6][512][384]
#define WW    5062656    // W bf16 [512][12][512] (1,572,864 float-slots)

// ---------------- K1: proj GEMM + bias + fused rotation + vT scatter ----------------
__global__ __launch_bounds__(256) void proj_gemm(
    const float* __restrict__ s,
    const float* __restrict__ wq, const float* __restrict__ bq,
    const float* __restrict__ wk, const float* __restrict__ bk,
    const float* __restrict__ wv, const float* __restrict__ bv,
    const float* __restrict__ wqp, const float* __restrict__ bqp,
    const float* __restrict__ wkp, const float* __restrict__ bkp,
    const float* __restrict__ wvp, const float* __restrict__ bvp,
    const float* __restrict__ rot, const float* __restrict__ trans,
    float* __restrict__ proj, float* __restrict__ vT)
{
    __shared__ float As[32*68];
    __shared__ float Ws[32*52];
    int tid = threadIdx.x;
    int gm0 = blockIdx.x * 64;
    int gc0 = blockIdx.y * 48;
    const float *w, *b; int ldw, lc0;
    if      (gc0 < 192) { w = wq;  b = bq;  ldw = 192; lc0 = gc0;       }
    else if (gc0 < 384) { w = wk;  b = bk;  ldw = 192; lc0 = gc0 - 192; }
    else if (gc0 < 576) { w = wv;  b = bv;  ldw = 192; lc0 = gc0 - 384; }
    else if (gc0 < 720) { w = wqp; b = bqp; ldw = 144; lc0 = gc0 - 576; }
    else if (gc0 < 864) { w = wkp; b = bkp; ldw = 144; lc0 = gc0 - 720; }
    else                { w = wvp; b = bvp; ldw = 288; lc0 = gc0 - 864; }

    int mi = tid >> 4, ni = tid & 15;
    int m0 = mi * 4, n0 = ni * 3;
    float acc[4][3] = {};

    for (int k0 = 0; k0 < CS; k0 += 32) {
        for (int idx = tid; idx < 2048; idx += 256) {
            int r = idx >> 5, c = idx & 31;
            As[c*68 + r] = s[(gm0 + r)*CS + k0 + c];
        }
        for (int idx = tid; idx < 1536; idx += 256) {
            int c = idx / 48, j = idx - c*48;
            Ws[c*52 + j] = w[(k0 + c)*ldw + lc0 + j];
        }
        __syncthreads();
        #pragma unroll 8
        for (int kk = 0; kk < 32; ++kk) {
            float4 a = *(const float4*)&As[kk*68 + m0];
            float w0 = Ws[kk*52 + n0], w1 = Ws[kk*52 + n0 + 1], w2 = Ws[kk*52 + n0 + 2];
            acc[0][0] += a.x*w0; acc[0][1] += a.x*w1; acc[0][2] += a.x*w2;
            acc[1][0] += a.y*w0; acc[1][1] += a.y*w1; acc[1][2] += a.y*w2;
            acc[2][0] += a.z*w0; acc[2][1] += a.z*w1; acc[2][2] += a.z*w2;
            acc[3][0] += a.w*w0; acc[3][1] += a.w*w1; acc[3][2] += a.w*w2;
        }
        __syncthreads();
    }

    float b0 = b[lc0 + n0], b1 = b[lc0 + n0 + 1], b2 = b[lc0 + n0 + 2];
    float outv[4][3];
    if (gc0 >= 576) {
        #pragma unroll
        for (int i = 0; i < 4; ++i) {
            int gm = gm0 + m0 + i;
            const float* R = rot + gm*9;
            const float* T = trans + gm*3;
            float x = acc[i][0] + b0, y = acc[i][1] + b1, zz = acc[i][2] + b2;
            outv[i][0] = R[0]*x + R[1]*y + R[2]*zz + T[0];
            outv[i][1] = R[3]*x + R[4]*y + R[5]*zz + T[1];
            outv[i][2] = R[6]*x + R[7]*y + R[8]*zz + T[2];
        }
    } else {
        #pragma unroll
        for (int i = 0; i < 4; ++i) {
            outv[i][0] = acc[i][0] + b0; outv[i][1] = acc[i][1] + b1; outv[i][2] = acc[i][2] + b2;
        }
    }
    #pragma unroll
    for (int i = 0; i < 4; ++i) {
        float* dst = proj + (size_t)(gm0 + m0 + i)*PROJW + gc0 + n0;
        dst[0] = outv[i][0]; dst[1] = outv[i][1]; dst[2] = outv[i][2];
    }
    if ((gc0 >= 384 && gc0 < 576) || gc0 >= 864) {
        int rbase = (gc0 < 576) ? (gc0 - 384) : (gc0 - 672);
        #pragma unroll
        for (int i = 0; i < 4; ++i)
            #pragma unroll
            for (int j = 0; j < 3; ++j)
                vT[(size_t)(rbase + n0 + j)*NN + gm0 + m0 + i] = outv[i][j];
    }
}

// ---------------- K2: scores (bias fused, mask applied) ----------------
__global__ __launch_bounds__(256) void score_kernel(
    const float* __restrict__ proj, const float* __restrict__ z,
    const int* __restrict__ mask,
    const float* __restrict__ wb, const float* __restrict__ bb,
    float* __restrict__ sc_out)
{
    int bx = blockIdx.x;
    int n = bx >> 1;
    int m = ((bx & 1) << 8) + threadIdx.x;
    int tid = threadIdx.x;
    __shared__ float s_q[192], s_qp[144], s_wb[CZ*NH], s_bb[NH];
    const float* prow = proj + (size_t)n*PROJW;
    for (int i = tid; i < 192; i += 256) s_q[i] = prow[i];
    for (int i = tid; i < 144; i += 256) s_qp[i] = prow[576 + i];
    for (int i = tid; i < CZ*NH; i += 256) s_wb[i] = wb[i];
    if (tid < NH) s_bb[tid] = bb[tid];
    __syncthreads();

    bool ok = (mask[n] != 0) && (mask[m] != 0);
    const float* krow  = proj + (size_t)m*PROJW + 192;
    const float* kprow = proj + (size_t)m*PROJW + 720;
    const float* zrow  = z + ((size_t)n*NN + m)*CZ;

    float acc[NH];
    #pragma unroll
    for (int h = 0; h < NH; ++h) acc[h] = s_bb[h];
    #pragma unroll 4
    for (int c4 = 0; c4 < 32; ++c4) {
        float4 zv = *(const float4*)(zrow + c4*4);
        const float* wbp = &s_wb[c4*48];
        #pragma unroll
        for (int e = 0; e < 4; ++e) {
            float zz = (&zv.x)[e];
            #pragma unroll
            for (int h = 0; h < NH; ++h) acc[h] += zz * wbp[e*12 + h];
        }
    }
    float sc[12];
    #pragma unroll
    for (int h = 0; h < NH; ++h) {
        const float* qh = &s_q[h*16];
        const float* kh = krow + h*16;
        float dot = 0.f;
        #pragma unroll
        for (int c4 = 0; c4 < 4; ++c4) {
            float4 kv = *(const float4*)(kh + c4*4);
            dot += qh[c4*4+0]*kv.x + qh[c4*4+1]*kv.y + qh[c4*4+2]*kv.z + qh[c4*4+3]*kv.w;
        }
        float pts = 0.f;
        const float* qph = &s_qp[h*12];
        const float* kph = kprow + h*12;
        #pragma unroll
        for (int j = 0; j < 12; ++j) { float d = qph[j] - kph[j]; pts += d*d; }
        float sv = dot*0.25f - 0.5f*pts + acc[h];
        sc[h] = ok ? sv : -1e30f;
    }
    float* dst = sc_out + ((size_t)n*NN + m)*12;
    *(float4*)(dst)     = make_float4(sc[0], sc[1], sc[2], sc[3]);
    *(float4*)(dst + 4) = make_float4(sc[4], sc[5], sc[6], sc[7]);
    *(float4*)(dst + 8) = make_float4(sc[8], sc[9], sc[10], sc[11]);
}

// ---------------- K3: softmax -> normalized W bf16 [n][h][m] ----------------
__global__ __launch_bounds__(256) void softmax_kernel(
    const float* __restrict__ sc, __hip_bfloat16* __restrict__ W)
{
    int n = blockIdx.x, tid = threadIdx.x;
    __shared__ float s_e[NN*16];
    __shared__ float s_red[16*NH];
    __shared__ float s_M[NH], s_Sinv[NH];

    const float4* g = (const float4*)(sc + (size_t)n*NN*12);
    for (int idx = tid; idx < 1536; idx += 256) {
        int m = idx/3, part = idx - m*3;
        *(float4*)&s_e[m*16 + part*4] = g[idx];
    }
    __syncthreads();
    if (tid < 192) {
        int i = tid / 12, h = tid - i*12;
        float mx = -1e30f;
        for (int mm = i*32; mm < i*32 + 32; ++mm) mx = fmaxf(mx, s_e[mm*16 + h]);
        s_red[tid] = mx;
    }
    __syncthreads();
    if (tid < NH) {
        float mx = -1e30f;
        #pragma unroll
        for (int i = 0; i < 16; ++i) mx = fmaxf(mx, s_red[i*12 + tid]);
        s_M[tid] = mx;
    }
    __syncthreads();
    {
        float M[12];
        #pragma unroll
        for (int h = 0; h < NH; ++h) M[h] = s_M[h];
        for (int r = 0; r < 2; ++r) {
            int m = tid + 256*r;
            float* row = &s_e[m*16];
            float4 a = *(float4*)row, b4 = *(float4*)(row+4), c4 = *(float4*)(row+8);
            a.x = __expf(a.x - M[0]);  a.y = __expf(a.y - M[1]);
            a.z = __expf(a.z - M[2]);  a.w = __expf(a.w - M[3]);
            b4.x = __expf(b4.x - M[4]); b4.y = __expf(b4.y - M[5]);
            b4.z = __expf(b4.z - M[6]); b4.w = __expf(b4.w - M[7]);
            c4.x = __expf(c4.x - M[8]); c4.y = __expf(c4.y - M[9]);
            c4.z = __expf(c4.z - M[10]); c4.w = __expf(c4.w - M[11]);
            *(float4*)row = a; *(float4*)(row+4) = b4; *(float4*)(row+8) = c4;
        }
    }
    __syncthreads();
    if (tid < 192) {
        int i = tid / 12, h = tid - i*12;
        float sm = 0.f;
        for (int mm = i*32; mm < i*32 + 32; ++mm) sm += s_e[mm*16 + h];
        s_red[tid] = sm;
    }
    __syncthreads();
    if (tid < NH) {
        float sm = 0.f;
        #pragma unroll
        for (int i = 0; i < 16; ++i) sm += s_red[i*12 + tid];
        s_Sinv[tid] = 1.0f / sm;
    }
    __syncthreads();
    __hip_bfloat16* Wn = W + (size_t)n*NH*NN;
    for (int idx = tid; idx < 6144; idx += 256) {
        int h = idx >> 9, m = idx & 511;
        Wn[idx] = __float2bfloat16(s_e[m*16 + h] * s_Sinv[h]);
    }
}

// ---------------- K4: v_out scalar+points GEMM per (h, n-tile) + transform epilogue ----------------
__global__ __launch_bounds__(256) void vout_gemm(
    const __hip_bfloat16* __restrict__ W, const float* __restrict__ vT,
    const float* __restrict__ rot, const float* __restrict__ trans,
    float* __restrict__ feat)
{
    __shared__ float Wt[32*68];   // [k][n] stride 68
    __shared__ float Bt[32*52];   // [k][lc] stride 52
    int tid = threadIdx.x;
    int n0 = blockIdx.x * 64;
    int h  = blockIdx.y;
    int ni = tid >> 4, ci = tid & 15;
    int m0 = ni * 4, c0 = ci * 3;
    float acc[4][3] = {};

    for (int k0 = 0; k0 < NN; k0 += 32) {
        // stage W tile: 64 n-rows x 32 k (bf16 pairs)
        const unsigned* Wu = (const unsigned*)W;
        for (int idx = tid; idx < 1024; idx += 256) {
            int r = idx >> 4, c2 = idx & 15;
            unsigned u = Wu[(size_t)(n0 + r)*3072 + h*256 + (k0 >> 1) + c2];
            Wt[(c2*2)*68 + r]     = __uint_as_float(u << 16);
            Wt[(c2*2 + 1)*68 + r] = __uint_as_float(u & 0xffff0000u);
        }
        // stage B tile: 32 k x 48 cols (cols 0-23 points, 24-39 scalar, 40-47 dummy)
        for (int idx = tid; idx < 1536; idx += 256) {
            int lc = idx >> 5, c = idx & 31;
            int vrow = (lc < 24) ? (192 + h*24 + lc) : ((lc < 40) ? (h*16 + lc - 24) : 0);
            Bt[c*52 + lc] = vT[(size_t)vrow*NN + k0 + c];
        }
        __syncthreads();
        #pragma unroll 8
        for (int kk = 0; kk < 32; ++kk) {
            float4 a = *(const float4*)&Wt[kk*68 + m0];
            float w0 = Bt[kk*52 + c0], w1 = Bt[kk*52 + c0 + 1], w2 = Bt[kk*52 + c0 + 2];
            acc[0][0] += a.x*w0; acc[0][1] += a.x*w1; acc[0][2] += a.x*w2;
            acc[1][0] += a.y*w0; acc[1][1] += a.y*w1; acc[1][2] += a.y*w2;
            acc[2][0] += a.z*w0; acc[2][1] += a.z*w1; acc[2][2] += a.z*w2;
            acc[3][0] += a.w*w0; acc[3][1] += a.w*w1; acc[3][2] += a.w*w2;
        }
        __syncthreads();
    }

    if (ci < 8) {
        // point triple p = ci (global frame) -> local + norm
        #pragma unroll
        for (int i = 0; i < 4; ++i) {
            int gn = n0 + m0 + i;
            const float* R = rot + gn*9;
            const float* T = trans + gn*3;
            float px = acc[i][0] - T[0], py = acc[i][1] - T[1], pz = acc[i][2] - T[2];
            float lx = R[0]*px + R[3]*py + R[6]*pz;
            float ly = R[1]*px + R[4]*py + R[7]*pz;
            float lz = R[2]*px + R[5]*py + R[8]*pz;
            float* fo = feat + (size_t)gn*FEAT + h*176;
            fo[16 + 3*ci]     = lx;
            fo[16 + 3*ci + 1] = ly;
            fo[16 + 3*ci + 2] = lz;
            fo[40 + ci] = sqrtf(lx*lx + ly*ly + lz*lz);
        }
    } else if (ci < 14) {
        #pragma unroll
        for (int i = 0; i < 4; ++i) {
            float* fo = feat + (size_t)(n0 + m0 + i)*FEAT + h*176;
            #pragma unroll
            for (int j = 0; j < 3; ++j) {
                int c = 3*ci - 24 + j;
                if (c < 16) fo[c] = acc[i][j];
            }
        }
    }
}

// ---------------- K5: pair features per n ----------------
#define SWS 520
__global__ __launch_bounds__(256) void pair_kernel(
    const __hip_bfloat16* __restrict__ W, const float* __restrict__ z,
    float* __restrict__ feat)
{
    int n = blockIdx.x, tid = threadIdx.x;
    __shared__ float s_W[NH*SWS];   // [h][m]; aliased by s_pair after final W read
    float* s_pair = s_W;            // [4][12][128] = 6144 <= 6240

    const unsigned* Wu = (const unsigned*)W + (size_t)n*3072;
    for (int idx = tid; idx < 3072; idx += 256) {
        int h = idx >> 8, m2 = idx & 255;
        unsigned u = Wu[idx];
        s_W[h*SWS + 2*m2]     = __uint_as_float(u << 16);
        s_W[h*SWS + 2*m2 + 1] = __uint_as_float(u & 0xffff0000u);
    }
    __syncthreads();

    int wave = tid >> 6, lane = tid & 63;
    int mbase = wave * 128;
    const float* zr = z + ((size_t)n*NN + mbase)*CZ;
    float p0[12] = {}, p1[12] = {};
    for (int mg = 0; mg < 32; ++mg) {
        float4 w4[12];
        #pragma unroll
        for (int h = 0; h < NH; ++h)
            w4[h] = *(const float4*)&s_W[h*SWS + mbase + mg*4];
        #pragma unroll
        for (int e = 0; e < 4; ++e) {
            int mm = mg*4 + e;
            float zv0 = zr[(size_t)mm*CZ + lane];
            float zv1 = zr[(size_t)mm*CZ + 64 + lane];
            #pragma unroll
            for (int h = 0; h < NH; ++h) {
                float wv = (&w4[h].x)[e];
                p0[h] += wv * zv0;
                p1[h] += wv * zv1;
            }
        }
    }
    __syncthreads();   // all W reads complete before aliased writes
    #pragma unroll
    for (int h = 0; h < NH; ++h) {
        s_pair[(wave*NH + h)*128 + lane]      = p0[h];
        s_pair[(wave*NH + h)*128 + 64 + lane] = p1[h];
    }
    __syncthreads();
    float* fout = feat + (size_t)n*FEAT;
    {
        int c = tid & 127, jh = tid >> 7;
        #pragma unroll
        for (int j = 0; j < 6; ++j) {
            int h = jh*6 + j;
            fout[h*176 + 48 + c] = s_pair[h*128 + c] + s_pair[(NH + h)*128 + c]
                                 + s_pair[(2*NH + h)*128 + c] + s_pair[(3*NH + h)*128 + c];
        }
    }
}

// ---------------- K6: out GEMM split-K partials ----------------
__global__ __launch_bounds__(256) void out_gemm(
    const float* __restrict__ feat, const float* __restrict__ wo,
    float* __restrict__ pout)
{
    __shared__ float As[16*68];
    __shared__ float Ws[16*68];
    int tid = threadIdx.x;
    int gm0 = blockIdx.x * 64, gn0 = blockIdx.y * 64;
    int kc = blockIdx.z;
    int kbase = kc * 352;
    int mi = tid >> 4, ni = tid & 15;
    int m0 = mi * 4, n0 = ni * 4;
    float acc[4][4] = {};

    for (int kt = 0; kt < 22; ++kt) {
        int k0 = kbase + kt*16;
        for (int idx = tid; idx < 1024; idx += 256) {
            int r = idx >> 4, c = idx & 15;
            As[c*68 + r] = feat[(size_t)(gm0 + r)*FEAT + k0 + c];
        }
        for (int idx = tid; idx < 1024; idx += 256) {
            int r = idx >> 6, c = idx & 63;
            Ws[r*68 + c] = wo[(size_t)(k0 + r)*OUTC + gn0 + c];
        }
        __syncthreads();
        #pragma unroll 8
        for (int kk = 0; kk < 16; ++kk) {
            float4 a = *(const float4*)&As[kk*68 + m0];
            float4 w = *(const float4*)&Ws[kk*68 + n0];
            acc[0][0] += a.x*w.x; acc[0][1] += a.x*w.y; acc[0][2] += a.x*w.z; acc[0][3] += a.x*w.w;
            acc[1][0] += a.y*w.x; acc[1][1] += a.y*w.y; acc[1][2] += a.y*w.z; acc[1][3] += a.y*w.w;
            acc[2][0] += a.z*w.x; acc[2][1] += a.z*w.y; acc[2][2] += a.z*w.z; acc[2][3] += a.z*w.w;
            acc[3][0] += a.w*w.x; acc[3][1] += a.w*w.y; acc[3][2] += a.w*w.z; acc[3][3] += a.w*w.w;
        }
        __syncthreads();
    }
    float* pb = pout + (size_t)kc * (NN*OUTC);
    #pragma unroll
    for (int i = 0; i < 4; ++i)
        *(float4*)&pb[(size_t)(gm0 + m0 + i)*OUTC + gn0 + n0] =
            make_float4(acc[i][0], acc[i][1], acc[i][2], acc[i][3]);
}

// ---------------- K7: reduce partials + bias ----------------
__global__ __launch_bounds__(256) void out_reduce(
    const float* __restrict__ pout, const float* __restrict__ bo,
    float* __restrict__ out)
{
    int idx4 = blockIdx.x * 256 + threadIdx.x;
    int col4 = idx4 % 96;
    const float4* b4 = (const float4*)bo;
    float4 acc = b4[col4];
    #pragma unroll
    for (int kc = 0; kc < 6; ++kc) {
        float4 p = ((const float4*)(pout + (size_t)kc*(NN*OUTC)))[idx4];
        acc.x += p.x; acc.y += p.y; acc.z += p.z; acc.w += p.w;
    }
    ((float4*)out)[idx4] = acc;
}

extern "C" void kernel_launch(void* const* d_in, const int* in_sizes, int n_in,
                              void* d_out, int out_size, void* d_ws, size_t ws_size,
                              hipStream_t stream) {
    (void)in_sizes; (void)n_in; (void)out_size; (void)ws_size;
    const float* s     = (const float*)d_in[0];
    const float* z     = (const float*)d_in[1];
    const float* trans = (const float*)d_in[2];
    const float* rot   = (const float*)d_in[3];
    const int*   mask  = (const int*)d_in[4];
    const float* wq    = (const float*)d_in[5];
    const float* bq    = (const float*)d_in[6];
    const float* wk    = (const float*)d_in[7];
    const float* bk    = (const float*)d_in[8];
    const float* wv    = (const float*)d_in[9];
    const float* bv    = (const float*)d_in[10];
    const float* wqp   = (const float*)d_in[11];
    const float* bqp   = (const float*)d_in[12];
    const float* wkp   = (const float*)d_in[13];
    const float* bkp   = (const float*)d_in[14];
    const float* wvp   = (const float*)d_in[15];
    const float* bvp   = (const float*)d_in[16];
    const float* wb    = (const float*)d_in[17];
    const float* bb    = (const float*)d_in[18];
    const float* wo    = (const float*)d_in[19];
    const float* bo    = (const float*)d_in[20];
    float* ws  = (float*)d_ws;
    float* out = (float*)d_out;
    __hip_bfloat16* Wbf = (__hip_bfloat16*)(ws + WW);

    proj_gemm<<<dim3(8, 24), 256, 0, stream>>>(
        s, wq, bq, wk, bk, wv, bv, wqp, bqp, wkp, bkp, wvp, bvp, rot, trans,
        ws + WPROJ, ws + WVT);
    score_kernel<<<1024, 256, 0, stream>>>(ws + WPROJ, z, mask, wb, bb, ws + WSC);
    softmax_kernel<<<NN, 256, 0, stream>>>(ws + WSC, Wbf);
    vout_gemm<<<dim3(8, 12), 256, 0, stream>>>(Wbf, ws + WVT, rot, trans, ws + WFEAT);
    pair_kernel<<<NN, 256, 0, stream>>>(Wbf, z, ws + WFEAT);
    out_gemm<<<dim3(8, 6, 6), 256, 0, stream>>>(ws + WFEAT, wo, ws + WSC);
    out_reduce<<<192, 256, 0, stream>>>(ws + WSC, bo, out);
}